// Round 7
// baseline (683.751 us; speedup 1.0000x reference)
//
#include <hip/hip_runtime.h>
#include <hip/hip_bf16.h>

#define NE 8
#define NT 16384
#define ND 512
#define NF 2048
#define BT 128

typedef __attribute__((ext_vector_type(8))) short bf16x8;
typedef __attribute__((ext_vector_type(4))) float f32x4;
typedef unsigned short u16;
typedef unsigned long long u64;

#define WAITV0() asm volatile("s_waitcnt vmcnt(0)" ::: "memory")
#define WAITL()  asm volatile("s_waitcnt lgkmcnt(0)" ::: "memory")

__device__ __forceinline__ u16 f2bf(float f) {
  union { float f; unsigned u; } c; c.f = f;
  unsigned u = c.u;
  return (u16)((u + 0x7FFFu + ((u >> 16) & 1u)) >> 16);
}

// gelu(x) = x * (1 - 1/(exp2(K1*x + K2*x^3) + 1)),  K1 = sqrt(2/pi)*2*log2e
__device__ __forceinline__ float gelu_fast(float x) {
  float x2 = x * x;
  float zp = x * __builtin_fmaf(0.10294325f, x2, 2.3022084f);
  float u = __builtin_amdgcn_exp2f(zp);
  float r = __builtin_amdgcn_rcpf(u + 1.0f);   // u=inf -> r=0 -> y=x
  return x * (1.0f - r);
}

__device__ __forceinline__ void gl_lds16(const void* g, void* l) {
  __builtin_amdgcn_global_load_lds(
      (const __attribute__((address_space(1))) unsigned int*)g,
      (__attribute__((address_space(3))) unsigned int*)l, 16, 0, 0);
}

// W1 [E][512 d][2048 f] -> panels (e, c=f/256, kb=d/64): [256 f][64 d] bf16 rows of
// 128 B, swizzle byte ^= (f&7)<<4. Panel 32 KB, 64 panels/expert (c major, kb minor).
__global__ void pack_w1(const float* __restrict__ in, u16* __restrict__ outp) {
  __shared__ float tile[32][33];
  int e = blockIdx.z, bx = blockIdx.x, by = blockIdx.y;  // bx: d/32 (16), by: f/32 (64)
  int d0 = bx * 32, f0 = by * 32;
  int tx = threadIdx.x & 31, ty = threadIdx.x >> 5;
  const float* ip = in + ((size_t)e * 512 + d0) * 2048 + f0;
  #pragma unroll
  for (int i = 0; i < 4; i++)
    tile[ty + i * 8][tx] = ip[(size_t)(ty + i * 8) * 2048 + tx];  // tile[d][f]
  __syncthreads();
  size_t pbase = (((size_t)e * 8 + (by >> 3)) * 8 + (bx >> 1)) * 32768;  // bytes
  int row = (by & 7) * 32 + tx;                 // f within panel
  int dby = (bx & 1) * 64 + ty * 8;             // d byte within 128-B row
  int byo = row * 128 + (dby ^ ((row & 7) << 4));
  union { u16 s[4]; ushort4 v; } o;
  #pragma unroll
  for (int j = 0; j < 4; j++) o.s[j] = f2bf(tile[ty * 4 + j][tx]);
  *(ushort4*)((char*)outp + pbase + byo) = o.v;
}

// W2 [E][2048 f][512 d] -> panels (e, c=f/256, kb=(f%256)/32): [512 d][32 f] bf16 rows
// of 64 B, swizzle byte ^= ((d>>1)&3)<<4. Panel 32 KB.
__global__ void pack_w2(const float* __restrict__ in, u16* __restrict__ outp) {
  __shared__ float tile[32][33];
  int e = blockIdx.z, bx = blockIdx.x, by = blockIdx.y;  // bx: f/32 (64), by: d/32 (16)
  int k0 = bx * 32, r0 = by * 32;
  int tx = threadIdx.x & 31, ty = threadIdx.x >> 5;
  const float* ip = in + ((size_t)e * 2048 + k0) * 512 + r0;
  #pragma unroll
  for (int i = 0; i < 4; i++)
    tile[ty + i * 8][tx] = ip[(size_t)(ty + i * 8) * 512 + tx];  // tile[f][d]
  __syncthreads();
  size_t pbase = (((size_t)e * 8 + (bx >> 3)) * 8 + (bx & 7)) * 32768;  // bytes
  int row = by * 32 + tx;                        // d within panel
  int byo = row * 64 + ((ty * 8) ^ (((row >> 1) & 3) << 4));
  union { u16 s[4]; ushort4 v; } o;
  #pragma unroll
  for (int j = 0; j < 4; j++) o.s[j] = f2bf(tile[ty * 4 + j][tx]);
  *(ushort4*)((char*)outp + pbase + byo) = o.v;
}

__global__ void x_to_bf16(const float* __restrict__ x, u16* __restrict__ xbf) {
  int i = blockIdx.x * 256 + threadIdx.x;
  float4 v = ((const float4*)x)[i];
  union { u16 s[4]; u64 ll; } o;
  o.s[0] = f2bf(v.x); o.s[1] = f2bf(v.y); o.s[2] = f2bf(v.z); o.s[3] = f2bf(v.w);
  ((u64*)xbf)[i] = o.ll;
}

__global__ void zero_unmasked(const int* __restrict__ mask, float4* __restrict__ out4) {
  int row = blockIdx.x * 2 + (threadIdx.x >> 7);
  if (mask[row]) return;  // masked rows fully written by moe_ffn
  out4[(size_t)row * 128 + (threadIdx.x & 127)] = float4{0.f, 0.f, 0.f, 0.f};
}

__global__ void compact_mask(const int* __restrict__ mask, int* __restrict__ idx,
                             int* __restrict__ counts) {
  int e = blockIdx.x;
  __shared__ int wsum[4];
  __shared__ int base;
  if (threadIdx.x == 0) base = 0;
  const int* m = mask + (size_t)e * NT;
  int lane = threadIdx.x & 63, w = threadIdx.x >> 6;
  for (int c0 = 0; c0 < NT; c0 += 256) {
    __syncthreads();
    int i = c0 + threadIdx.x;
    int mi = (m[i] != 0);
    unsigned long long b = __ballot(mi);
    if (lane == 0) wsum[w] = __popcll(b);
    __syncthreads();
    int off = base;
    for (int ww = 0; ww < w; ww++) off += wsum[ww];
    off += __popcll(b & ((1ull << lane) - 1ull));
    if (mi) idx[(size_t)e * NT + off] = i;
    __syncthreads();
    if (threadIdx.x == 0) base += wsum[0] + wsum[1] + wsum[2] + wsum[3];
  }
  __syncthreads();
  if (threadIdx.x == 0) counts[e] = base;
}

// Fused masked-FFN. BT=128 tokens/block, 8 waves, f-chunks of 256.
// G1: K-step 64 d (32 KB W1 panel + 16 KB x panel), 8 steps/chunk, 32 MFMA/step.
// G2: K-step 32 f (32 KB W2 panel), 8 steps/chunk, 32 MFMA/step.
// 2-slot single-barrier pipeline: STAGE(next->s^1); ds_read+MFMA(s); drain; barrier.
__launch_bounds__(512, 2)
__global__ void moe_ffn(const u16* __restrict__ xbf, const u16* __restrict__ W1p,
                        const float* __restrict__ b1f, const u16* __restrict__ W2p,
                        const float* __restrict__ b2f,
                        const int* __restrict__ idx, const int* __restrict__ counts,
                        float* __restrict__ out) {
  // ---- identity prefix mapping: active work = contiguous low block IDs ----
  int b = blockIdx.x;
  int e = 0, r0 = 0, start = 0; bool act = false;
  #pragma unroll
  for (int ee = 0; ee < 8; ee++) {
    int nb = (counts[ee] + (BT - 1)) >> 7;
    if (!act && b < start + nb) { e = ee; r0 = (b - start) << 7; act = true; }
    start += nb;
  }
  if (!act) return;
  int rem = counts[e] - r0; if (rem > BT) rem = BT;

  // LDS = exactly 160 KB
  __shared__ __align__(16) u16 arena[2 * 16384];  // 64 KB: 2 x 32 KB weight slots
  __shared__ __align__(16) u16 xp[2 * 8192];      // 32 KB: 2 x 16 KB x panels
  __shared__ __align__(16) u16 hs[BT * 256];      // 64 KB: h^T chunk [t][f]

  int tid = threadIdx.x, lane = tid & 63, w = tid >> 6;
  int wt = w & 1, wfd = w >> 1;   // t-split 2, f/d-split 4
  int l15 = lane & 15, l4 = lane >> 4;

  const int* idxe = idx + (size_t)e * NT + r0;

  // x stage source: wave w stages x-panel rows w*16 .. w*16+15 (2 calls of 8 rows)
  int xrow0 = w * 16 + (lane >> 3);
  int xrow1 = xrow0 + 8;
  int tok0 = idxe[xrow0 < rem ? xrow0 : rem - 1];
  int tok1 = idxe[xrow1 < rem ? xrow1 : rem - 1];
  int xsw = ((lane & 7) * 16) ^ (((lane >> 3) & 7) << 4);  // row&7 == lane>>3
  const char* xbyte = (const char*)xbf;
  size_t xsrc0 = (size_t)tok0 * (ND * 2) + xsw;
  size_t xsrc1 = (size_t)tok1 * (ND * 2) + xsw;

  // ds-read byte offsets (slot-relative)
  int aoff1[4][2], boffx[4][2], aoff2[8], tbase[4], tswz[4];
  #pragma unroll
  for (int i = 0; i < 4; i++) {
    int rf = wfd * 64 + i * 16 + l15;
    int t  = wt * 64 + i * 16 + l15;
    #pragma unroll
    for (int hh = 0; hh < 2; hh++) {
      aoff1[i][hh] = rf * 128 + ((hh * 64 + l4 * 16) ^ ((rf & 7) << 4));
      boffx[i][hh] = t * 128 + ((hh * 64 + l4 * 16) ^ ((t & 7) << 4));
    }
    tbase[i] = t * 512; tswz[i] = (t & 7) << 4;
  }
  #pragma unroll
  for (int i = 0; i < 8; i++) {
    int rd = wfd * 128 + i * 16 + l15;
    aoff2[i] = rd * 64 + ((l4 * 16) ^ (((rd >> 1) & 3) << 4));
  }

  const char* w1b = (const char*)W1p + (size_t)e * (64 * 32768);
  const char* w2b = (const char*)W2p + (size_t)e * (64 * 32768);
  char* arenaB = (char*)arena;
  char* xpB = (char*)xp;
  char* hsB = (char*)hs;

  auto STAGE1 = [&](int c, int kb, int s) {   // W1 panel (c,kb) -> arena[s]; x kb -> xp[s]
    const char* pb = w1b + (((size_t)c * 8 + kb) << 15);
    char* lb = arenaB + s * 32768 + w * 4096;
    #pragma unroll
    for (int j = 0; j < 4; j++)
      gl_lds16(pb + w * 4096 + j * 1024 + lane * 16, lb + j * 1024);
    char* xlb = xpB + s * 16384 + w * 2048;
    gl_lds16(xbyte + xsrc0 + kb * 128, xlb);
    gl_lds16(xbyte + xsrc1 + kb * 128, xlb + 1024);
  };
  auto STAGE2 = [&](int c, int kb, int s) {   // W2 panel (c,kb) -> arena[s]
    const char* pb = w2b + (((size_t)c * 8 + kb) << 15);
    char* lb = arenaB + s * 32768 + w * 4096;
    #pragma unroll
    for (int j = 0; j < 4; j++)
      gl_lds16(pb + w * 4096 + j * 1024 + lane * 16, lb + j * 1024);
  };

  // prologue
  STAGE1(0, 0, 0);
  WAITV0();
  __builtin_amdgcn_s_barrier();

  f32x4 yacc[8][4];
  #pragma unroll
  for (int i = 0; i < 8; i++)
    #pragma unroll
    for (int t = 0; t < 4; t++) yacc[i][t] = (f32x4)(0.0f);

  for (int c = 0; c < 8; ++c) {
    // ---- GEMM1: h^T[256 f x 128 t] = W1c^T x x^T, K=512 over 8 panels of 64 ----
    f32x4 acc1[4][4];
    #pragma unroll
    for (int i = 0; i < 4; i++)
      #pragma unroll
      for (int t = 0; t < 4; t++) acc1[i][t] = (f32x4)(0.0f);

    for (int kb = 0; kb < 8; ++kb) {
      int s = kb & 1;
      if (kb < 7) STAGE1(c, kb + 1, s ^ 1);  // slot s^1 readers finished at step kb-1
      else        STAGE2(c, 0, 0);           // G2 p0 -> slot 0 (read at kb=6, done)
      const char* lb = arenaB + s * 32768;
      const char* lx = xpB + s * 16384;
      #pragma unroll
      for (int hh = 0; hh < 2; hh++) {
        bf16x8 a[4], bb[4];
        #pragma unroll
        for (int i = 0; i < 4; i++) a[i] = *(const bf16x8*)(lb + aoff1[i][hh]);
        #pragma unroll
        for (int t = 0; t < 4; t++) bb[t] = *(const bf16x8*)(lx + boffx[t][hh]);
        #pragma unroll
        for (int i = 0; i < 4; i++)
          #pragma unroll
          for (int t = 0; t < 4; t++)
            acc1[i][t] = __builtin_amdgcn_mfma_f32_16x16x32_bf16(a[i], bb[t], acc1[i][t], 0, 0, 0);
      }
      WAITL();
      if (kb < 7) WAITV0();   // kb=7's stage (G2 p0) rides through the GELU phase
      __builtin_amdgcn_s_barrier();
    }

    // ---- GELU + b1 -> hs[t][f] ----
    #pragma unroll
    for (int i = 0; i < 4; i++) {
      int fb = wfd * 64 + i * 16 + l4 * 4;
      f32x4 bv = *(const f32x4*)(b1f + (size_t)e * NF + c * 256 + fb);
      #pragma unroll
      for (int t = 0; t < 4; t++) {
        union { u16 s[4]; u64 ll; } pk;
        #pragma unroll
        for (int j = 0; j < 4; j++)
          pk.s[j] = f2bf(gelu_fast(acc1[i][t][j] + bv[j]));
        *(u64*)(hsB + tbase[t] + ((fb * 2) ^ tswz[t])) = pk.ll;
      }
    }
    WAITL(); WAITV0();   // hs writes done; G2 p0 + bv loads drained
    __builtin_amdgcn_s_barrier();

    // ---- GEMM2: y^T[512 d x 128 t] += W2c^T x h, K=256 over 8 panels of 32 ----
    for (int kb = 0; kb < 8; ++kb) {
      int s = kb & 1;
      if (kb < 7)     STAGE2(c, kb + 1, s ^ 1);  // slot s^1 readers done at kb-1
      else if (c < 7) STAGE1(c + 1, 0, 0);       // next-chunk G1 p0 + x p0 (slot 0 free)
      const char* lb = arenaB + s * 32768;
      bf16x8 a[8], bb[4];
      #pragma unroll
      for (int i = 0; i < 8; i++) a[i] = *(const bf16x8*)(lb + aoff2[i]);
      #pragma unroll
      for (int t = 0; t < 4; t++)
        bb[t] = *(const bf16x8*)(hsB + tbase[t] + ((kb * 64 + l4 * 16) ^ tswz[t]));
      #pragma unroll
      for (int i = 0; i < 8; i++)
        #pragma unroll
        for (int t = 0; t < 4; t++)
          yacc[i][t] = __builtin_amdgcn_mfma_f32_16x16x32_bf16(a[i], bb[t], yacc[i][t], 0, 0, 0);
      WAITL(); WAITV0();
      __builtin_amdgcn_s_barrier();
    }
  }

  // ---- epilogue: per-token contiguous float4 stores (+b2), guard t < rem ----
  #pragma unroll
  for (int i = 0; i < 8; i++) {
    int db = wfd * 128 + i * 16 + l4 * 4;
    f32x4 b2v = *(const f32x4*)(b2f + (size_t)e * ND + db);
    #pragma unroll
    for (int t = 0; t < 4; t++) {
      int tt = wt * 64 + t * 16 + l15;
      if (tt < rem) {
        int tok = idxe[tt];
        f32x4 v;
        #pragma unroll
        for (int j = 0; j < 4; j++) v[j] = yacc[i][t][j] + b2v[j];
        *(f32x4*)(out + ((size_t)e * NT + tok) * ND + db) = v;
      }
    }
  }
}

extern "C" void kernel_launch(void* const* d_in, const int* in_sizes, int n_in,
                              void* d_out, int out_size, void* d_ws, size_t ws_size,
                              hipStream_t stream) {
  const float* x  = (const float*)d_in[0];
  const float* W1 = (const float*)d_in[1];
  const float* b1 = (const float*)d_in[2];
  const float* W2 = (const float*)d_in[3];
  const float* b2 = (const float*)d_in[4];
  const int* mask = (const int*)d_in[5];

  char* ws = (char*)d_ws;
  int* counts = (int*)ws;                                   // 1 KiB region
  int* idx    = (int*)(ws + 1024);                          // 512 KiB
  u16* W1p    = (u16*)(ws + 1024 + (size_t)NE * NT * 4);    // 16 MiB
  u16* W2p    = W1p + (size_t)NE * NF * ND;                 // 16 MiB
  u16* xbf    = W2p + (size_t)NE * ND * NF;                 // 16 MiB

  zero_unmasked<<<dim3(NE * NT / 2), dim3(256), 0, stream>>>(mask, (float4*)d_out);
  pack_w1<<<dim3(16, 64, NE), dim3(256), 0, stream>>>(W1, W1p);
  pack_w2<<<dim3(64, 16, NE), dim3(256), 0, stream>>>(W2, W2p);
  x_to_bf16<<<dim3(NT * ND / 4 / 256), dim3(256), 0, stream>>>(x, xbf);
  compact_mask<<<dim3(NE), dim3(256), 0, stream>>>(mask, idx, counts);
  moe_ffn<<<dim3(1024), dim3(512), 0, stream>>>(xbf, W1p, b1, W2p, b2, idx, counts,
                                                (float*)d_out);
}

// Round 8
// 652.052 us; speedup vs baseline: 1.0486x; 1.0486x over previous
//
#include <hip/hip_runtime.h>
#include <hip/hip_bf16.h>

#define NE 8
#define NT 16384
#define ND 512
#define NF 2048
#define BT 128

typedef __attribute__((ext_vector_type(8))) short bf16x8;
typedef __attribute__((ext_vector_type(4))) float f32x4;
typedef unsigned short u16;
typedef unsigned long long u64;

#define WAITV(n) asm volatile("s_waitcnt vmcnt(" #n ")" ::: "memory")
#define WAITL()  asm volatile("s_waitcnt lgkmcnt(0)" ::: "memory")

__device__ __forceinline__ u16 f2bf(float f) {
  union { float f; unsigned u; } c; c.f = f;
  unsigned u = c.u;
  return (u16)((u + 0x7FFFu + ((u >> 16) & 1u)) >> 16);
}

// gelu(x) = x * (1 - 1/(exp2(K1*x + K2*x^3) + 1)),  K1 = sqrt(2/pi)*2*log2e
__device__ __forceinline__ float gelu_fast(float x) {
  float x2 = x * x;
  float zp = x * __builtin_fmaf(0.10294325f, x2, 2.3022084f);
  float u = __builtin_amdgcn_exp2f(zp);
  float r = __builtin_amdgcn_rcpf(u + 1.0f);   // u=inf -> r=0 -> y=x
  return x * (1.0f - r);
}

__device__ __forceinline__ void gl_lds16(const void* g, void* l) {
  __builtin_amdgcn_global_load_lds(
      (const __attribute__((address_space(1))) unsigned int*)g,
      (__attribute__((address_space(3))) unsigned int*)l, 16, 0, 0);
}

// Pack weights into staged-panel images (swizzle pre-applied, byte-exact LDS image).
// MODE 0: W1 [E][512 d][2048 f] -> panels (e, c=f/256, kb=d/32): [256 f][32 d] bf16, 16 KB.
// MODE 1: W2 [E][2048 f][512 d] -> panels (e, c=f/256, kb=(f%256)/32): [512 d][32 f] bf16, 32 KB.
template<int MODE>
__global__ void pack_w(const float* __restrict__ in, u16* __restrict__ outp) {
  constexpr int K = MODE ? 2048 : 512;
  constexpr int R = MODE ? 512 : 2048;
  __shared__ float tile[32][33];
  int e = blockIdx.z, bx = blockIdx.x, by = blockIdx.y;
  int k0 = bx * 32, r0 = by * 32;
  int tx = threadIdx.x & 31, ty = threadIdx.x >> 5;
  const float* ip = in + ((size_t)e * K + k0) * R + r0;
  #pragma unroll
  for (int i = 0; i < 4; i++)
    tile[ty + i * 8][tx] = ip[(size_t)(ty + i * 8) * R + tx];
  __syncthreads();
  size_t base; int rowb;
  if (MODE == 0) { base = (((size_t)e * 8 + (by >> 3)) * 16 + bx) * 8192; rowb = (by & 7) * 32; }
  else           { base = (((size_t)e * 8 + (bx >> 3)) * 8 + (bx & 7)) * 16384; rowb = by * 32; }
  int row = rowb + tx;
  int byo = row * 64 + ((ty * 8) ^ (((row >> 1) & 3) << 4));
  union { u16 s[4]; ushort4 v; } o;
  #pragma unroll
  for (int j = 0; j < 4; j++) o.s[j] = f2bf(tile[ty * 4 + j][tx]);
  *(ushort4*)((char*)outp + base * 2 + byo) = o.v;
}

__global__ void x_to_bf16(const float* __restrict__ x, u16* __restrict__ xbf) {
  int i = blockIdx.x * 256 + threadIdx.x;
  float4 v = ((const float4*)x)[i];
  union { u16 s[4]; u64 ll; } o;
  o.s[0] = f2bf(v.x); o.s[1] = f2bf(v.y); o.s[2] = f2bf(v.z); o.s[3] = f2bf(v.w);
  ((u64*)xbf)[i] = o.ll;
}

__global__ void zero_unmasked(const int* __restrict__ mask, float4* __restrict__ out4) {
  int row = blockIdx.x * 2 + (threadIdx.x >> 7);
  if (mask[row]) return;  // masked rows fully written by moe_ffn
  out4[(size_t)row * 128 + (threadIdx.x & 127)] = float4{0.f, 0.f, 0.f, 0.f};
}

__global__ void compact_mask(const int* __restrict__ mask, int* __restrict__ idx,
                             int* __restrict__ counts) {
  int e = blockIdx.x;
  __shared__ int wsum[4];
  __shared__ int base;
  if (threadIdx.x == 0) base = 0;
  const int* m = mask + (size_t)e * NT;
  int lane = threadIdx.x & 63, w = threadIdx.x >> 6;
  for (int c0 = 0; c0 < NT; c0 += 256) {
    __syncthreads();
    int i = c0 + threadIdx.x;
    int mi = (m[i] != 0);
    unsigned long long b = __ballot(mi);
    if (lane == 0) wsum[w] = __popcll(b);
    __syncthreads();
    int off = base;
    for (int ww = 0; ww < w; ww++) off += wsum[ww];
    off += __popcll(b & ((1ull << lane) - 1ull));
    if (mi) idx[(size_t)e * NT + off] = i;
    __syncthreads();
    if (threadIdx.x == 0) base += wsum[0] + wsum[1] + wsum[2] + wsum[3];
  }
  __syncthreads();
  if (threadIdx.x == 0) counts[e] = base;
}

// Fused masked-FFN. BT=128 tokens/block, 8 waves, f-chunks of 256, K-panels of 32.
// 3-slot counted-vmcnt pipeline (T3+T4): per step:
//   WAITV(in-flight-after-current); barrier; STAGE(kb+2 -> slot (kb+2)%3); ds_read+MFMA(kb).
// Slot being staged was last read at step kb-1 (barrier guarantees readers done).
__launch_bounds__(512, 2)
__global__ void moe_ffn(const u16* __restrict__ xbf, const u16* __restrict__ W1p,
                        const float* __restrict__ b1f, const u16* __restrict__ W2p,
                        const float* __restrict__ b2f,
                        const int* __restrict__ idx, const int* __restrict__ counts,
                        float* __restrict__ out) {
  // ---- identity prefix mapping: active work = contiguous low block IDs ----
  int b = blockIdx.x;
  int e = 0, r0 = 0, start = 0; bool act = false;
  #pragma unroll
  for (int ee = 0; ee < 8; ee++) {
    int nb = (counts[ee] + (BT - 1)) >> 7;
    if (!act && b < start + nb) { e = ee; r0 = (b - start) << 7; act = true; }
    start += nb;
  }
  if (!act) return;
  int rem = counts[e] - r0; if (rem > BT) rem = BT;

  // LDS = 160 KB: 3 x 32 KB slots (G1: 16 KB W1 + 8 KB x + 8 KB pad; G2: 32 KB W2) + hs
  __shared__ __align__(16) u16 arena[3 * 16384];  // 96 KB
  __shared__ __align__(16) u16 hs[BT * 256];      // 64 KB: h^T chunk [t][f]

  int tid = threadIdx.x, lane = tid & 63, w = tid >> 6;
  int wt = w & 1, wfd = w >> 1;   // t-split 2, f/d-split 4
  int l15 = lane & 15, l4 = lane >> 4;

  const int* idxe = idx + (size_t)e * NT + r0;

  // x stage source: wave w stages x-panel rows w*16 .. w*16+15 (one gl_lds16)
  int xrow = w * 16 + (lane >> 2);
  int tok = idxe[xrow < rem ? xrow : rem - 1];
  int xsw = ((lane & 3) * 16) ^ (((xrow >> 1) & 3) << 4);
  const char* xbyte = (const char*)xbf;
  size_t xsrc = (size_t)tok * (ND * 2) + xsw;

  // ds-read byte offsets (slot-relative)
  int aoff1[4], boffx[4], aoff2[8], tbase[4], tswz[4];
  #pragma unroll
  for (int i = 0; i < 4; i++) {
    int rf = wfd * 64 + i * 16 + l15;
    aoff1[i] = rf * 64 + ((l4 * 16) ^ (((rf >> 1) & 3) << 4));
    int t = wt * 64 + i * 16 + l15;
    boffx[i] = 16384 + t * 64 + ((l4 * 16) ^ (((t >> 1) & 3) << 4));
    tbase[i] = t * 512; tswz[i] = (t & 7) << 4;
  }
  #pragma unroll
  for (int i = 0; i < 8; i++) {
    int rd = wfd * 128 + i * 16 + l15;
    aoff2[i] = rd * 64 + ((l4 * 16) ^ (((rd >> 1) & 3) << 4));
  }

  const char* w1b = (const char*)W1p + (size_t)e * (8 * 16 * 16384);
  const char* w2b = (const char*)W2p + (size_t)e * (8 * 8 * 32768);
  char* arenaB = (char*)arena;
  char* hsB = (char*)hs;

  auto STAGE1 = [&](int c, int kb, int s) {   // 3 insts/wave: W1 16KB + x 8KB
    const char* pb = w1b + (((size_t)c * 16 + kb) << 14);
    char* lb = arenaB + s * 32768;
    gl_lds16(pb + w * 2048 + lane * 16, lb + w * 2048);
    gl_lds16(pb + w * 2048 + 1024 + lane * 16, lb + w * 2048 + 1024);
    gl_lds16(xbyte + xsrc + kb * 64, lb + 16384 + w * 1024);
  };
  auto STAGE2 = [&](int c, int kb, int s) {   // 4 insts/wave: W2 32KB
    const char* pb = w2b + (((size_t)c * 8 + kb) << 15);
    char* lb = arenaB + s * 32768 + w * 4096;
    #pragma unroll
    for (int j = 0; j < 4; j++)
      gl_lds16(pb + w * 4096 + j * 1024 + lane * 16, lb + j * 1024);
  };

  // prologue: panels 0,1 of chunk 0
  STAGE1(0, 0, 0);
  STAGE1(0, 1, 1);

  f32x4 yacc[8][4];
  #pragma unroll
  for (int i = 0; i < 8; i++)
    #pragma unroll
    for (int t = 0; t < 4; t++) yacc[i][t] = (f32x4)(0.0f);

  for (int c = 0; c < 8; ++c) {
    // ---- GEMM1: h^T[256 f x 128 t] = W1c^T x x^T, K=512 over 16 panels of 32 ----
    f32x4 acc1[4][4];
    #pragma unroll
    for (int i = 0; i < 4; i++)
      #pragma unroll
      for (int t = 0; t < 4; t++) acc1[i][t] = (f32x4)(0.0f);

    for (int kb = 0; kb < 16; ++kb) {
      int s = kb % 3;
      // in-flight after this wait: stage(kb+1); last step also has G2 p0 (4)
      if (kb == 15) WAITV(4);
      else          WAITV(3);
      __builtin_amdgcn_s_barrier();
      if (kb < 14)       STAGE1(c, kb + 2, (kb + 2) % 3);
      else if (kb == 14) STAGE2(c, 0, 1);   // slot 1: readers (kb=13) done
      else               STAGE2(c, 1, 2);   // slot 2: readers (kb=14) done
      const char* lb = arenaB + s * 32768;
      bf16x8 a[4], bb[4];
      #pragma unroll
      for (int i = 0; i < 4; i++) a[i] = *(const bf16x8*)(lb + aoff1[i]);
      #pragma unroll
      for (int t = 0; t < 4; t++) bb[t] = *(const bf16x8*)(lb + boffx[t]);
      #pragma unroll
      for (int i = 0; i < 4; i++)
        #pragma unroll
        for (int t = 0; t < 4; t++)
          acc1[i][t] = __builtin_amdgcn_mfma_f32_16x16x32_bf16(a[i], bb[t], acc1[i][t], 0, 0, 0);
    }

    // ---- GELU + b1 -> hs[t][f] (G2 p0/p1 in flight through this phase) ----
    #pragma unroll
    for (int i = 0; i < 4; i++) {
      int fb = wfd * 64 + i * 16 + l4 * 4;
      f32x4 bv = *(const f32x4*)(b1f + (size_t)e * NF + c * 256 + fb);
      #pragma unroll
      for (int t = 0; t < 4; t++) {
        union { u16 s[4]; u64 ll; } pk;
        #pragma unroll
        for (int j = 0; j < 4; j++)
          pk.s[j] = f2bf(gelu_fast(acc1[i][t][j] + bv[j]));
        *(u64*)(hsB + tbase[t] + ((fb * 2) ^ tswz[t])) = pk.ll;
      }
    }
    WAITL();
    __builtin_amdgcn_s_barrier();

    // ---- GEMM2: y^T[512 d x 128 t] += W2c^T x h, K=256 over 8 panels of 32 ----
    for (int kb = 0; kb < 8; ++kb) {
      int s = (1 + kb) % 3;
      // in-flight after wait: stage(kb+1) (4); last step: G1 p0 of next chunk (3)
      if (kb == 7) WAITV(3);
      else         WAITV(4);
      __builtin_amdgcn_s_barrier();
      if (kb < 6)          STAGE2(c, kb + 2, (1 + kb + 2) % 3);
      else if (kb == 6) {  if (c < 7) STAGE1(c + 1, 0, 0); }   // slot 0: readers (kb=5) done
      else              {  if (c < 7) STAGE1(c + 1, 1, 1); }   // slot 1: readers (kb=6) done
      const char* lb = arenaB + s * 32768;
      bf16x8 a[8], bb[4];
      #pragma unroll
      for (int i = 0; i < 8; i++) a[i] = *(const bf16x8*)(lb + aoff2[i]);
      #pragma unroll
      for (int t = 0; t < 4; t++)
        bb[t] = *(const bf16x8*)(hsB + tbase[t] + ((kb * 64 + l4 * 16) ^ tswz[t]));
      #pragma unroll
      for (int i = 0; i < 8; i++)
        #pragma unroll
        for (int t = 0; t < 4; t++)
          yacc[i][t] = __builtin_amdgcn_mfma_f32_16x16x32_bf16(a[i], bb[t], yacc[i][t], 0, 0, 0);
    }
  }

  // ---- epilogue: per-token contiguous float4 stores (+b2), guard t < rem ----
  #pragma unroll
  for (int i = 0; i < 8; i++) {
    int db = wfd * 128 + i * 16 + l4 * 4;
    f32x4 b2v = *(const f32x4*)(b2f + (size_t)e * ND + db);
    #pragma unroll
    for (int t = 0; t < 4; t++) {
      int tt = wt * 64 + t * 16 + l15;
      if (tt < rem) {
        int tk = idxe[tt];
        f32x4 v;
        #pragma unroll
        for (int j = 0; j < 4; j++) v[j] = yacc[i][t][j] + b2v[j];
        *(f32x4*)(out + ((size_t)e * NT + tk) * ND + db) = v;
      }
    }
  }
}

extern "C" void kernel_launch(void* const* d_in, const int* in_sizes, int n_in,
                              void* d_out, int out_size, void* d_ws, size_t ws_size,
                              hipStream_t stream) {
  const float* x  = (const float*)d_in[0];
  const float* W1 = (const float*)d_in[1];
  const float* b1 = (const float*)d_in[2];
  const float* W2 = (const float*)d_in[3];
  const float* b2 = (const float*)d_in[4];
  const int* mask = (const int*)d_in[5];

  char* ws = (char*)d_ws;
  int* counts = (int*)ws;                                   // 1 KiB region
  int* idx    = (int*)(ws + 1024);                          // 512 KiB
  u16* W1p    = (u16*)(ws + 1024 + (size_t)NE * NT * 4);    // 16 MiB
  u16* W2p    = W1p + (size_t)NE * NF * ND;                 // 16 MiB
  u16* xbf    = W2p + (size_t)NE * ND * NF;                 // 16 MiB

  zero_unmasked<<<dim3(NE * NT / 2), dim3(256), 0, stream>>>(mask, (float4*)d_out);
  pack_w<0><<<dim3(16, 64, NE), dim3(256), 0, stream>>>(W1, W1p);
  pack_w<1><<<dim3(64, 16, NE), dim3(256), 0, stream>>>(W2, W2p);
  x_to_bf16<<<dim3(NT * ND / 4 / 256), dim3(256), 0, stream>>>(x, xbf);
  compact_mask<<<dim3(NE), dim3(256), 0, stream>>>(mask, idx, counts);
  moe_ffn<<<dim3(1024), dim3(512), 0, stream>>>(xbf, W1p, b1, W2p, b2, idx, counts,
                                                (float*)d_out);
}

// Round 9
// 621.626 us; speedup vs baseline: 1.0999x; 1.0489x over previous
//
#include <hip/hip_runtime.h>
#include <hip/hip_bf16.h>

#define NE 8
#define NT 16384
#define ND 512
#define NF 2048
#define BT 64

typedef __attribute__((ext_vector_type(8))) short bf16x8;
typedef __attribute__((ext_vector_type(4))) float f32x4;
typedef unsigned short u16;
typedef unsigned long long u64;

#define WAITV0() asm volatile("s_waitcnt vmcnt(0)" ::: "memory")
#define WAITL()  asm volatile("s_waitcnt lgkmcnt(0)" ::: "memory")

__device__ __forceinline__ u16 f2bf(float f) {
  union { float f; unsigned u; } c; c.f = f;
  unsigned u = c.u;
  return (u16)((u + 0x7FFFu + ((u >> 16) & 1u)) >> 16);
}

__device__ __forceinline__ float bf2f(u16 v) {
  union { unsigned u; float f; } c; c.u = ((unsigned)v) << 16;
  return c.f;
}

// gelu(x) = x * (1 - 1/(exp2(K1*x + K2*x^3) + 1)),  K1 = sqrt(2/pi)*2*log2e
__device__ __forceinline__ float gelu_fast(float x) {
  float x2 = x * x;
  float zp = x * __builtin_fmaf(0.10294325f, x2, 2.3022084f);
  float u = __builtin_amdgcn_exp2f(zp);
  float r = __builtin_amdgcn_rcpf(u + 1.0f);   // u=inf -> r=0 -> y=x
  return x * (1.0f - r);
}

__device__ __forceinline__ void gl_lds16(const void* g, void* l) {
  __builtin_amdgcn_global_load_lds(
      (const __attribute__((address_space(1))) unsigned int*)g,
      (__attribute__((address_space(3))) unsigned int*)l, 16, 0, 0);
}

// W1 [E][512 d][2048 f] -> panels (e, c=f/256, kb=d/32): [256 f][32 d] bf16, 16 KB.
__global__ void pack_w1(const float* __restrict__ in, u16* __restrict__ outp) {
  __shared__ float tile[32][33];
  int e = blockIdx.z, bx = blockIdx.x, by = blockIdx.y;  // bx: d/32 (16), by: f/32 (64)
  int k0 = bx * 32, r0 = by * 32;
  int tx = threadIdx.x & 31, ty = threadIdx.x >> 5;
  const float* ip = in + ((size_t)e * 512 + k0) * 2048 + r0;
  #pragma unroll
  for (int i = 0; i < 4; i++)
    tile[ty + i * 8][tx] = ip[(size_t)(ty + i * 8) * 2048 + tx];  // tile[d][f]
  __syncthreads();
  size_t base = (((size_t)e * 8 + (by >> 3)) * 16 + bx) * 16384;  // bytes
  int row = (by & 7) * 32 + tx;  // f within panel
  int byo = row * 64 + ((ty * 8) ^ (((row >> 1) & 3) << 4));
  union { u16 s[4]; ushort4 v; } o;
  #pragma unroll
  for (int j = 0; j < 4; j++) o.s[j] = f2bf(tile[ty * 4 + j][tx]);
  *(ushort4*)((char*)outp + base + byo) = o.v;
}

// W2 [E][2048 f][512 d] -> panels (e, c=f/256, dh=d/256, kb=(f%256)/32):
// [256 d][32 f] bf16 rows of 64 B, swizzle byte ^= ((d>>1)&3)<<4. Panel 16 KB.
__global__ void pack_w2(const float* __restrict__ in, u16* __restrict__ outp) {
  __shared__ float tile[32][33];
  int e = blockIdx.z, bx = blockIdx.x, by = blockIdx.y;  // bx: f/32 (64), by: d/32 (16)
  int k0 = bx * 32, r0 = by * 32;
  int tx = threadIdx.x & 31, ty = threadIdx.x >> 5;
  const float* ip = in + ((size_t)e * 2048 + k0) * 512 + r0;
  #pragma unroll
  for (int i = 0; i < 4; i++)
    tile[ty + i * 8][tx] = ip[(size_t)(ty + i * 8) * 512 + tx];  // tile[f][d]
  __syncthreads();
  int c = bx >> 3, kb = bx & 7, dh = by >> 3;
  size_t base = ((((size_t)e * 8 + c) * 2 + dh) * 8 + kb) * 16384;  // bytes
  int row = (by & 7) * 32 + tx;  // d within 256-row panel
  int byo = row * 64 + ((ty * 8) ^ (((row >> 1) & 3) << 4));
  union { u16 s[4]; ushort4 v; } o;
  #pragma unroll
  for (int j = 0; j < 4; j++) o.s[j] = f2bf(tile[ty * 4 + j][tx]);
  *(ushort4*)((char*)outp + base + byo) = o.v;
}

__global__ void x_to_bf16(const float* __restrict__ x, u16* __restrict__ xbf) {
  int i = blockIdx.x * 256 + threadIdx.x;
  float4 v = ((const float4*)x)[i];
  union { u16 s[4]; u64 ll; } o;
  o.s[0] = f2bf(v.x); o.s[1] = f2bf(v.y); o.s[2] = f2bf(v.z); o.s[3] = f2bf(v.w);
  ((u64*)xbf)[i] = o.ll;
}

__global__ void bias_bf16(const float* __restrict__ b1, const float* __restrict__ b2,
                          u16* __restrict__ b1bf, u16* __restrict__ b2bf) {
  int i = blockIdx.x * 256 + threadIdx.x;
  if (i < NE * NF) b1bf[i] = f2bf(b1[i]);
  else             b2bf[i - NE * NF] = f2bf(b2[i - NE * NF]);
}

__global__ void zero_unmasked(const int* __restrict__ mask, float4* __restrict__ out4) {
  int row = blockIdx.x * 2 + (threadIdx.x >> 7);
  if (mask[row]) return;  // masked rows fully written by moe_ffn
  out4[(size_t)row * 128 + (threadIdx.x & 127)] = float4{0.f, 0.f, 0.f, 0.f};
}

__global__ void compact_mask(const int* __restrict__ mask, int* __restrict__ idx,
                             int* __restrict__ counts) {
  int e = blockIdx.x;
  __shared__ int wsum[4];
  __shared__ int base;
  if (threadIdx.x == 0) base = 0;
  const int* m = mask + (size_t)e * NT;
  int lane = threadIdx.x & 63, w = threadIdx.x >> 6;
  for (int c0 = 0; c0 < NT; c0 += 256) {
    __syncthreads();
    int i = c0 + threadIdx.x;
    int mi = (m[i] != 0);
    unsigned long long b = __ballot(mi);
    if (lane == 0) wsum[w] = __popcll(b);
    __syncthreads();
    int off = base;
    for (int ww = 0; ww < w; ww++) off += wsum[ww];
    off += __popcll(b & ((1ull << lane) - 1ull));
    if (mi) idx[(size_t)e * NT + off] = i;
    __syncthreads();
    if (threadIdx.x == 0) base += wsum[0] + wsum[1] + wsum[2] + wsum[3];
  }
  __syncthreads();
  if (threadIdx.x == 0) counts[e] = base;
}

// Fused masked-FFN. 4 waves, BT=64 tokens/block, 77 KB LDS -> 2 blocks/CU (TLP hides
// staging latency across independent blocks). f-chunks of 256, K-panels of 32.
// 2-slot pipeline: STAGE(next -> s^1); compute(s); vmcnt(0); barrier.
__launch_bounds__(256, 2)
__global__ void moe_ffn(const u16* __restrict__ xbf, const u16* __restrict__ W1p,
                        const u16* __restrict__ W2p, const u16* __restrict__ b1bf,
                        const u16* __restrict__ b2bf,
                        const int* __restrict__ idx, const int* __restrict__ counts,
                        float* __restrict__ out) {
  // ---- identity prefix mapping: active work = contiguous low block IDs ----
  int b = blockIdx.x;
  int e = 0, r0 = 0, start = 0; bool act = false;
  #pragma unroll
  for (int ee = 0; ee < 8; ee++) {
    int nb = (counts[ee] + (BT - 1)) >> 6;
    if (!act && b < start + nb) { e = ee; r0 = (b - start) << 6; act = true; }
    start += nb;
  }
  if (!act) return;
  int rem = counts[e] - r0; if (rem > BT) rem = BT;

  // LDS = 77 KB total
  __shared__ __align__(16) u16 wsl[2][8192];   // 32 KB: 2 x 16 KB weight slots
  __shared__ __align__(16) u16 xsl[2][2048];   // 8 KB:  2 x 4 KB x panels
  __shared__ __align__(16) u16 hs[BT * 256];   // 32 KB: h^T chunk [t][f]
  __shared__ __align__(16) u16 b1s[NF];        // 4 KB
  __shared__ __align__(16) u16 b2s[ND];        // 1 KB

  int tid = threadIdx.x, lane = tid & 63, w = tid >> 6;  // 4 waves: f/d split
  int l15 = lane & 15, l4 = lane >> 4;

  const int* idxe = idx + (size_t)e * NT + r0;

  // x stage source: wave w stages x-panel rows w*16 .. w*16+15 (one gl_lds16)
  int xrow = w * 16 + (lane >> 2);
  int tok = idxe[xrow < rem ? xrow : rem - 1];
  int xsw = ((lane & 3) * 16) ^ (((xrow >> 1) & 3) << 4);
  const char* xbyte = (const char*)xbf;
  size_t xsrc = (size_t)tok * (ND * 2) + xsw;

  // ds-read byte offsets
  int aoff1[4], boffx[4], aoff2[4], tbase[4], tswz[4];
  #pragma unroll
  for (int i = 0; i < 4; i++) {
    int rf = w * 64 + i * 16 + l15;                     // f row (G1 A)
    aoff1[i] = rf * 64 + ((l4 * 16) ^ (((rf >> 1) & 3) << 4));
    int rd = w * 64 + i * 16 + l15;                     // d row within 256-panel (G2 A)
    aoff2[i] = rd * 64 + ((l4 * 16) ^ (((rd >> 1) & 3) << 4));
    int t = i * 16 + l15;                               // token col (shared by waves)
    boffx[i] = t * 64 + ((l4 * 16) ^ (((t >> 1) & 3) << 4));
    tbase[i] = t * 512; tswz[i] = (t & 7) << 4;
  }

  const char* w1b = (const char*)W1p + (size_t)e * (8 * 16 * 16384);
  const char* w2b = (const char*)W2p + (size_t)e * (8 * 16 * 16384);
  char* hsB = (char*)hs;

  auto STAGE1 = [&](int c, int kb, int s) {   // 5 insts/wave: W1 16KB + x 4KB
    const char* pb = w1b + (((size_t)c * 16 + kb) << 14);
    char* lb = (char*)wsl[s] + w * 4096;
    #pragma unroll
    for (int j = 0; j < 4; j++)
      gl_lds16(pb + w * 4096 + j * 1024 + lane * 16, lb + j * 1024);
    gl_lds16(xbyte + xsrc + kb * 64, (char*)xsl[s] + w * 1024);
  };
  auto STAGE2 = [&](int c, int dh, int kb, int s) {   // 4 insts/wave: W2 half-panel 16KB
    const char* pb = w2b + ((((size_t)c * 2 + dh) * 8 + kb) << 14);
    char* lb = (char*)wsl[s] + w * 4096;
    #pragma unroll
    for (int j = 0; j < 4; j++)
      gl_lds16(pb + w * 4096 + j * 1024 + lane * 16, lb + j * 1024);
  };

  // prologue: biases (bf16) + G1 panel 0
  gl_lds16((const char*)(b1bf + (size_t)e * NF) + w * 1024, (char*)b1s + w * 1024);
  if (w == 0) gl_lds16((const char*)(b2bf + (size_t)e * ND), (char*)b2s);
  STAGE1(0, 0, 0);
  WAITV0();
  __builtin_amdgcn_s_barrier();

  f32x4 yacc[2][4][4];
  #pragma unroll
  for (int dh = 0; dh < 2; dh++)
    #pragma unroll
    for (int i = 0; i < 4; i++)
      #pragma unroll
      for (int t = 0; t < 4; t++) yacc[dh][i][t] = (f32x4)(0.0f);

  for (int c = 0; c < 8; ++c) {
    // ---- GEMM1: h^T[256 f x 64 t] = W1c^T x x^T, K=512 over 16 panels of 32 ----
    f32x4 acc1[4][4];
    #pragma unroll
    for (int i = 0; i < 4; i++)
      #pragma unroll
      for (int t = 0; t < 4; t++) acc1[i][t] = (f32x4)(0.0f);

    for (int kb = 0; kb < 16; ++kb) {
      int s = kb & 1;
      if (kb < 15) STAGE1(c, kb + 1, s ^ 1);  // slot s^1 readers finished at kb-1
      const char* lb = (const char*)wsl[s];
      const char* lx = (const char*)xsl[s];
      bf16x8 a[4], bb[4];
      #pragma unroll
      for (int i = 0; i < 4; i++) a[i] = *(const bf16x8*)(lb + aoff1[i]);
      #pragma unroll
      for (int t = 0; t < 4; t++) bb[t] = *(const bf16x8*)(lx + boffx[t]);
      #pragma unroll
      for (int i = 0; i < 4; i++)
        #pragma unroll
        for (int t = 0; t < 4; t++)
          acc1[i][t] = __builtin_amdgcn_mfma_f32_16x16x32_bf16(a[i], bb[t], acc1[i][t], 0, 0, 0);
      WAITV0();
      __builtin_amdgcn_s_barrier();
    }

    // ---- GELU + b1 -> hs[t][f]; stage G2 (dh0,p0) under the VALU work ----
    STAGE2(c, 0, 0, 0);   // slot 0: G1 kb=15 read slot 1; slot 0 readers done at kb=14
    #pragma unroll
    for (int i = 0; i < 4; i++) {
      int fb = w * 64 + i * 16 + l4 * 4;
      u64 braw = *(const u64*)((const char*)b1s + c * 512 + fb * 2);
      #pragma unroll
      for (int t = 0; t < 4; t++) {
        union { u16 s[4]; u64 ll; } pk;
        #pragma unroll
        for (int j = 0; j < 4; j++)
          pk.s[j] = f2bf(gelu_fast(acc1[i][t][j] + bf2f((u16)(braw >> (16 * j)))));
        *(u64*)(hsB + tbase[t] + ((fb * 2) ^ tswz[t])) = pk.ll;
      }
    }
    WAITL(); WAITV0();
    __builtin_amdgcn_s_barrier();

    // ---- GEMM2: y^T[512 d x 64 t] += W2c^T x h, 2 d-halves x 8 panels of 32 f ----
    #pragma unroll
    for (int m = 0; m < 16; ++m) {
      int dh = m >> 3, kb = m & 7;
      int s = m & 1;
      if (m < 15)     STAGE2(c, (m + 1) >> 3, (m + 1) & 7, s ^ 1);
      else if (c < 7) STAGE1(c + 1, 0, 0);    // slot 0 readers done at m=14
      const char* lb = (const char*)wsl[s];
      bf16x8 a[4], bb[4];
      #pragma unroll
      for (int i = 0; i < 4; i++) a[i] = *(const bf16x8*)(lb + aoff2[i]);
      #pragma unroll
      for (int t = 0; t < 4; t++)
        bb[t] = *(const bf16x8*)(hsB + tbase[t] + ((kb * 64 + l4 * 16) ^ tswz[t]));
      #pragma unroll
      for (int i = 0; i < 4; i++)
        #pragma unroll
        for (int t = 0; t < 4; t++)
          yacc[dh][i][t] = __builtin_amdgcn_mfma_f32_16x16x32_bf16(a[i], bb[t], yacc[dh][i][t], 0, 0, 0);
      WAITV0();
      __builtin_amdgcn_s_barrier();
    }
  }

  // ---- epilogue: per-token contiguous float4 stores (+b2), guard t < rem ----
  #pragma unroll
  for (int dh = 0; dh < 2; dh++)
    #pragma unroll
    for (int i = 0; i < 4; i++) {
      int d0 = dh * 256 + w * 64 + i * 16 + l4 * 4;
      u64 braw = *(const u64*)((const char*)b2s + d0 * 2);
      f32x4 b2v;
      #pragma unroll
      for (int j = 0; j < 4; j++) b2v[j] = bf2f((u16)(braw >> (16 * j)));
      #pragma unroll
      for (int t = 0; t < 4; t++) {
        int tt = t * 16 + l15;
        if (tt < rem) {
          int tk = idxe[tt];
          f32x4 v;
          #pragma unroll
          for (int j = 0; j < 4; j++) v[j] = yacc[dh][i][t][j] + b2v[j];
          *(f32x4*)(out + ((size_t)e * NT + tk) * ND + d0) = v;
        }
      }
    }
}

extern "C" void kernel_launch(void* const* d_in, const int* in_sizes, int n_in,
                              void* d_out, int out_size, void* d_ws, size_t ws_size,
                              hipStream_t stream) {
  const float* x  = (const float*)d_in[0];
  const float* W1 = (const float*)d_in[1];
  const float* b1 = (const float*)d_in[2];
  const float* W2 = (const float*)d_in[3];
  const float* b2 = (const float*)d_in[4];
  const int* mask = (const int*)d_in[5];

  char* ws = (char*)d_ws;
  int* counts = (int*)ws;                                   // 1 KiB region
  int* idx    = (int*)(ws + 1024);                          // 512 KiB
  u16* W1p    = (u16*)(ws + 1024 + (size_t)NE * NT * 4);    // 16 MiB
  u16* W2p    = W1p + (size_t)NE * NF * ND;                 // 16 MiB
  u16* xbf    = W2p + (size_t)NE * ND * NF;                 // 16 MiB
  u16* b1bf   = xbf + (size_t)NT * ND;                      // 32 KiB
  u16* b2bf   = b1bf + (size_t)NE * NF;                     // 8 KiB

  zero_unmasked<<<dim3(NE * NT / 2), dim3(256), 0, stream>>>(mask, (float4*)d_out);
  pack_w1<<<dim3(16, 64, NE), dim3(256), 0, stream>>>(W1, W1p);
  pack_w2<<<dim3(64, 16, NE), dim3(256), 0, stream>>>(W2, W2p);
  x_to_bf16<<<dim3(NT * ND / 4 / 256), dim3(256), 0, stream>>>(x, xbf);
  bias_bf16<<<dim3((NE * (NF + ND)) / 256), dim3(256), 0, stream>>>(b1, b2, b1bf, b2bf);
  compact_mask<<<dim3(NE), dim3(256), 0, stream>>>(mask, idx, counts);
  moe_ffn<<<dim3(1024), dim3(256), 0, stream>>>(xbf, W1p, W2p, b1bf, b2bf, idx, counts,
                                                (float*)d_out);
}

// Round 10
// 478.914 us; speedup vs baseline: 1.4277x; 1.2980x over previous
//
#include <hip/hip_runtime.h>
#include <hip/hip_bf16.h>

#define NE 8
#define NT 16384
#define ND 512
#define NF 2048
#define BT 64

typedef __attribute__((ext_vector_type(8))) short bf16x8;
typedef __attribute__((ext_vector_type(4))) float f32x4;
typedef unsigned short u16;
typedef unsigned long long u64;

#define SBAR()  __builtin_amdgcn_s_barrier()
#define WAITL() asm volatile("s_waitcnt lgkmcnt(0)" ::: "memory")
#define WAITV0() asm volatile("s_waitcnt vmcnt(0)" ::: "memory")
#define SCHED0() __builtin_amdgcn_sched_barrier(0)

__device__ __forceinline__ u16 f2bf(float f) {
  union { float f; unsigned u; } c; c.f = f;
  unsigned u = c.u;
  return (u16)((u + 0x7FFFu + ((u >> 16) & 1u)) >> 16);
}

__device__ __forceinline__ float bf2f(u16 v) {
  union { unsigned u; float f; } c; c.u = ((unsigned)v) << 16;
  return c.f;
}

// gelu(x) = x * (1 - 1/(exp2(K1*x + K2*x^3) + 1)),  K1 = sqrt(2/pi)*2*log2e
__device__ __forceinline__ float gelu_fast(float x) {
  float x2 = x * x;
  float zp = x * __builtin_fmaf(0.10294325f, x2, 2.3022084f);
  float u = __builtin_amdgcn_exp2f(zp);
  float r = __builtin_amdgcn_rcpf(u + 1.0f);   // u=inf -> r=0 -> y=x
  return x * (1.0f - r);
}

__device__ __forceinline__ void gl_lds16(const void* g, void* l) {
  __builtin_amdgcn_global_load_lds(
      (const __attribute__((address_space(1))) unsigned int*)g,
      (__attribute__((address_space(3))) unsigned int*)l, 16, 0, 0);
}

// W1 [E][512 d][2048 f] -> panels (e, c=f/256, kb=d/32): [256 f][32 d] bf16, 16 KB, linear.
__global__ void pack_w1(const float* __restrict__ in, u16* __restrict__ outp) {
  __shared__ float tile[32][33];
  int e = blockIdx.z, bx = blockIdx.x, by = blockIdx.y;  // bx: d/32 (16), by: f/32 (64)
  int d0 = bx * 32, f0 = by * 32;
  int tx = threadIdx.x & 31, ty = threadIdx.x >> 5;
  const float* ip = in + ((size_t)e * 512 + d0) * 2048 + f0;
  #pragma unroll
  for (int i = 0; i < 4; i++)
    tile[ty + i * 8][tx] = ip[(size_t)(ty + i * 8) * 2048 + tx];  // tile[d][f]
  __syncthreads();
  size_t base = (((size_t)e * 8 + (by >> 3)) * 16 + bx) * 16384;  // bytes
  int row = (by & 7) * 32 + tx;                                   // f within panel
  int byo = row * 64 + ty * 8;                                    // d bytes, linear
  union { u16 s[4]; ushort4 v; } o;
  #pragma unroll
  for (int j = 0; j < 4; j++) o.s[j] = f2bf(tile[ty * 4 + j][tx]);
  *(ushort4*)((char*)outp + base + byo) = o.v;
}

// W2 [E][2048 f][512 d] -> panels (e, c=f/256, kb=(f%256)/32): [512 d][32 f] bf16, 32 KB, linear.
__global__ void pack_w2(const float* __restrict__ in, u16* __restrict__ outp) {
  __shared__ float tile[32][33];
  int e = blockIdx.z, bx = blockIdx.x, by = blockIdx.y;  // bx: f/32 (64), by: d/32 (16)
  int k0 = bx * 32, r0 = by * 32;
  int tx = threadIdx.x & 31, ty = threadIdx.x >> 5;
  const float* ip = in + ((size_t)e * 2048 + k0) * 512 + r0;
  #pragma unroll
  for (int i = 0; i < 4; i++)
    tile[ty + i * 8][tx] = ip[(size_t)(ty + i * 8) * 512 + tx];  // tile[f][d]
  __syncthreads();
  int c = bx >> 3, kb = bx & 7;
  size_t base = (((size_t)e * 8 + c) * 8 + kb) * 32768;  // bytes
  int row = by * 32 + tx;                                 // d within panel (0..511)
  int byo = row * 64 + ty * 8;                            // f bytes, linear
  union { u16 s[4]; ushort4 v; } o;
  #pragma unroll
  for (int j = 0; j < 4; j++) o.s[j] = f2bf(tile[ty * 4 + j][tx]);
  *(ushort4*)((char*)outp + base + byo) = o.v;
}

__global__ void x_to_bf16(const float* __restrict__ x, u16* __restrict__ xbf) {
  int i = blockIdx.x * 256 + threadIdx.x;
  float4 v = ((const float4*)x)[i];
  union { u16 s[4]; u64 ll; } o;
  o.s[0] = f2bf(v.x); o.s[1] = f2bf(v.y); o.s[2] = f2bf(v.z); o.s[3] = f2bf(v.w);
  ((u64*)xbf)[i] = o.ll;
}

__global__ void bias_bf16(const float* __restrict__ b1, const float* __restrict__ b2,
                          u16* __restrict__ b1bf, u16* __restrict__ b2bf) {
  int i = blockIdx.x * 256 + threadIdx.x;
  if (i < NE * NF) b1bf[i] = f2bf(b1[i]);
  else             b2bf[i - NE * NF] = f2bf(b2[i - NE * NF]);
}

__global__ void zero_unmasked(const int* __restrict__ mask, float4* __restrict__ out4) {
  int row = blockIdx.x * 2 + (threadIdx.x >> 7);
  if (mask[row]) return;  // masked rows fully written by moe_ffn
  out4[(size_t)row * 128 + (threadIdx.x & 127)] = float4{0.f, 0.f, 0.f, 0.f};
}

__global__ void compact_mask(const int* __restrict__ mask, int* __restrict__ idx,
                             int* __restrict__ counts) {
  int e = blockIdx.x;
  __shared__ int wsum[4];
  __shared__ int base;
  if (threadIdx.x == 0) base = 0;
  const int* m = mask + (size_t)e * NT;
  int lane = threadIdx.x & 63, w = threadIdx.x >> 6;
  for (int c0 = 0; c0 < NT; c0 += 256) {
    __syncthreads();
    int i = c0 + threadIdx.x;
    int mi = (m[i] != 0);
    unsigned long long b = __ballot(mi);
    if (lane == 0) wsum[w] = __popcll(b);
    __syncthreads();
    int off = base;
    for (int ww = 0; ww < w; ww++) off += wsum[ww];
    off += __popcll(b & ((1ull << lane) - 1ull));
    if (mi) idx[(size_t)e * NT + off] = i;
    __syncthreads();
    if (threadIdx.x == 0) base += wsum[0] + wsum[1] + wsum[2] + wsum[3];
  }
  __syncthreads();
  if (threadIdx.x == 0) counts[e] = base;
}

// Fused masked-FFN. BT=64 tokens/block, 8 waves (2/SIMD). Weights stream DIRECTLY
// global->VGPR with rolling prefetch rings (compiler-counted vmcnt); LDS holds only
// the shared operands: x (staged once), h (per f-chunk), biases. 2 barriers per chunk.
__launch_bounds__(512, 2)
__global__ void moe_ffn(const u16* __restrict__ xbf, const u16* __restrict__ W1p,
                        const u16* __restrict__ W2p, const u16* __restrict__ b1bf,
                        const u16* __restrict__ b2bf,
                        const int* __restrict__ idx, const int* __restrict__ counts,
                        float* __restrict__ out) {
  // ---- identity prefix mapping: active work = contiguous low block IDs ----
  int b = blockIdx.x;
  int e = 0, r0 = 0, start = 0; bool act = false;
  #pragma unroll
  for (int ee = 0; ee < 8; ee++) {
    int nb = (counts[ee] + (BT - 1)) >> 6;
    if (!act && b < start + nb) { e = ee; r0 = (b - start) << 6; act = true; }
    start += nb;
  }
  if (!act) return;
  int rem = counts[e] - r0; if (rem > BT) rem = BT;

  // LDS = 101.25 KB -> 1 block/CU, 8 waves = 2/SIMD
  __shared__ __align__(16) u16 xs[BT * 512];   // 64 KB, x^T tile (swizzled rows)
  __shared__ __align__(16) u16 hs[BT * 256];   // 32 KB, h chunk [t][f]
  __shared__ __align__(16) u16 b1s[NF];        // 4 KB
  __shared__ __align__(16) u16 b2s[ND];        // 1 KB

  int tid = threadIdx.x, lane = tid & 63, w = tid >> 6;
  int l15 = lane & 15, l4 = lane >> 4;
  int tswz = (l15 & 7) << 4;                   // row-swizzle for all shared reads

  const int* idxe = idx + (size_t)e * NT + r0;
  const char* xb = (const char*)xbf;

  // ---- stage xs once: wave w stages rows w*8 .. w*8+7 (1 KB each, swizzled src) ----
  #pragma unroll
  for (int j = 0; j < 8; j++) {
    int r = w * 8 + j;
    int tok = idxe[r < rem ? r : rem - 1];
    gl_lds16(xb + (size_t)tok * 1024 + ((lane * 16) ^ (j << 4)),
             (char*)xs + r * 1024);
  }
  if (w < 4) gl_lds16((const char*)(b1bf + (size_t)e * NF) + w * 1024, (char*)b1s + w * 1024);
  if (w == 4) gl_lds16((const char*)(b2bf + (size_t)e * ND), (char*)b2s);
  WAITV0();
  SBAR();

  const char* w1e = (const char*)W1p + (size_t)e * (8 * 16 * 16384);
  const char* w2e = (const char*)W2p + (size_t)e * (8 * 8 * 32768);
  int laneoff = l15 * 64 + l4 * 16;            // per-lane byte offset inside a row-block
  char* hsB = (char*)hs;
  const char* xsB = (const char*)xs;

  // per-thread token-frag bases
  int xrow[4], hrow[4];
  #pragma unroll
  for (int t = 0; t < 4; t++) {
    xrow[t] = (t * 16 + l15) * 1024;
    hrow[t] = (t * 16 + l15) * 512;
  }

  f32x4 yacc[4][4];
  #pragma unroll
  for (int m = 0; m < 4; m++)
    #pragma unroll
    for (int t = 0; t < 4; t++) yacc[m][t] = (f32x4)(0.0f);

  for (int c = 0; c < 8; ++c) {
    // ================= GEMM1: h[256 f x 64 t], K=512, 16 steps =================
    // wave w owns f rows w*32..+31 (M=2). A ring 8-deep, direct global->VGPR.
    f32x4 acc1[2][4];
    #pragma unroll
    for (int m = 0; m < 2; m++)
      #pragma unroll
      for (int t = 0; t < 4; t++) acc1[m][t] = (f32x4)(0.0f);

    {
      const char* pb = w1e + (size_t)c * (16 * 16384) + w * 2048 + laneoff;
      bf16x8 A[8][2];
      #pragma unroll
      for (int p = 0; p < 8; p++)
        #pragma unroll
        for (int m = 0; m < 2; m++)
          A[p][m] = *(const bf16x8*)(pb + p * 16384 + m * 1024);
      #pragma unroll
      for (int kb = 0; kb < 16; ++kb) {
        bf16x8 B[4];
        #pragma unroll
        for (int t = 0; t < 4; t++)
          B[t] = *(const bf16x8*)(xsB + xrow[t] + ((kb * 64 + l4 * 16) ^ tswz));
        #pragma unroll
        for (int m = 0; m < 2; m++)
          #pragma unroll
          for (int t = 0; t < 4; t++)
            acc1[m][t] = __builtin_amdgcn_mfma_f32_16x16x32_bf16(A[kb & 7][m], B[t],
                                                                 acc1[m][t], 0, 0, 0);
        if (kb < 8) {
          #pragma unroll
          for (int m = 0; m < 2; m++)
            A[kb & 7][m] = *(const bf16x8*)(pb + (kb + 8) * 16384 + m * 1024);
        }
      }
    }

    // ---- GELU + b1 -> hs[t][f] (hs free: prev chunk's G2 ended with barrier) ----
    #pragma unroll
    for (int i = 0; i < 2; i++) {
      int fb = w * 32 + i * 16 + l4 * 4;
      u64 braw = *(const u64*)((const char*)b1s + c * 512 + fb * 2);
      #pragma unroll
      for (int t = 0; t < 4; t++) {
        union { u16 s[4]; u64 ll; } pk;
        #pragma unroll
        for (int j = 0; j < 4; j++)
          pk.s[j] = f2bf(gelu_fast(acc1[i][t][j] + bf2f((u16)(braw >> (16 * j)))));
        *(u64*)(hsB + hrow[t] + ((fb * 2) ^ tswz)) = pk.ll;
      }
    }
    WAITL(); SCHED0();
    SBAR();

    // ================= GEMM2: y[512 d x 64 t] +=, K=256, 8 steps =================
    // wave w owns d rows w*64..+63 (M=4). A ring 4-deep.
    {
      const char* pb = w2e + (size_t)c * (8 * 32768) + w * 4096 + laneoff;
      bf16x8 A2[4][4];
      #pragma unroll
      for (int p = 0; p < 4; p++)
        #pragma unroll
        for (int m = 0; m < 4; m++)
          A2[p][m] = *(const bf16x8*)(pb + p * 32768 + m * 1024);
      #pragma unroll
      for (int kb = 0; kb < 8; ++kb) {
        bf16x8 B[4];
        #pragma unroll
        for (int t = 0; t < 4; t++)
          B[t] = *(const bf16x8*)(hsB + hrow[t] + ((kb * 64 + l4 * 16) ^ tswz));
        #pragma unroll
        for (int m = 0; m < 4; m++)
          #pragma unroll
          for (int t = 0; t < 4; t++)
            yacc[m][t] = __builtin_amdgcn_mfma_f32_16x16x32_bf16(A2[kb & 3][m], B[t],
                                                                 yacc[m][t], 0, 0, 0);
        if (kb < 4) {
          #pragma unroll
          for (int m = 0; m < 4; m++)
            A2[kb & 3][m] = *(const bf16x8*)(pb + (kb + 4) * 32768 + m * 1024);
        }
      }
    }
    WAITL(); SCHED0();
    SBAR();
  }

  // ---- epilogue: per-token contiguous float4 stores (+b2), guard t < rem ----
  #pragma unroll
  for (int m = 0; m < 4; m++) {
    int d0 = w * 64 + m * 16 + l4 * 4;
    u64 braw = *(const u64*)((const char*)b2s + d0 * 2);
    f32x4 b2v;
    #pragma unroll
    for (int j = 0; j < 4; j++) b2v[j] = bf2f((u16)(braw >> (16 * j)));
    #pragma unroll
    for (int t = 0; t < 4; t++) {
      int tt = t * 16 + l15;
      if (tt < rem) {
        int tk = idxe[tt];
        f32x4 v;
        #pragma unroll
        for (int j = 0; j < 4; j++) v[j] = yacc[m][t][j] + b2v[j];
        *(f32x4*)(out + ((size_t)e * NT + tk) * ND + d0) = v;
      }
    }
  }
}

extern "C" void kernel_launch(void* const* d_in, const int* in_sizes, int n_in,
                              void* d_out, int out_size, void* d_ws, size_t ws_size,
                              hipStream_t stream) {
  const float* x  = (const float*)d_in[0];
  const float* W1 = (const float*)d_in[1];
  const float* b1 = (const float*)d_in[2];
  const float* W2 = (const float*)d_in[3];
  const float* b2 = (const float*)d_in[4];
  const int* mask = (const int*)d_in[5];

  char* ws = (char*)d_ws;
  int* counts = (int*)ws;                                   // 1 KiB region
  int* idx    = (int*)(ws + 1024);                          // 512 KiB
  u16* W1p    = (u16*)(ws + 1024 + (size_t)NE * NT * 4);    // 16 MiB
  u16* W2p    = W1p + (size_t)NE * NF * ND;                 // 16 MiB
  u16* xbf    = W2p + (size_t)NE * ND * NF;                 // 16 MiB
  u16* b1bf   = xbf + (size_t)NT * ND;                      // 32 KiB
  u16* b2bf   = b1bf + (size_t)NE * NF;                     // 8 KiB

  zero_unmasked<<<dim3(NE * NT / 2), dim3(256), 0, stream>>>(mask, (float4*)d_out);
  pack_w1<<<dim3(16, 64, NE), dim3(256), 0, stream>>>(W1, W1p);
  pack_w2<<<dim3(64, 16, NE), dim3(256), 0, stream>>>(W2, W2p);
  x_to_bf16<<<dim3(NT * ND / 4 / 256), dim3(256), 0, stream>>>(x, xbf);
  bias_bf16<<<dim3((NE * (NF + ND)) / 256), dim3(256), 0, stream>>>(b1, b2, b1bf, b2bf);
  compact_mask<<<dim3(NE), dim3(256), 0, stream>>>(mask, idx, counts);
  moe_ffn<<<dim3(2048), dim3(512), 0, stream>>>(xbf, W1p, W2p, b1bf, b2bf, idx, counts,
                                                (float*)d_out);
}

// Round 11
// 373.060 us; speedup vs baseline: 1.8328x; 1.2837x over previous
//
#include <hip/hip_runtime.h>
#include <hip/hip_bf16.h>

#define NE 8
#define TOK 16384
#define ND 512
#define NF 2048
#define HP 4608   // padded compact rows per expert in h (cnt ~4096+-9sigma)
#define MT 36     // HP/128 m-tiles

typedef __attribute__((ext_vector_type(8))) short bf16x8;
typedef __attribute__((ext_vector_type(4))) float f32x4;
typedef unsigned short u16;
typedef unsigned long long u64;

__device__ __forceinline__ u16 f2bf(float f) {
  union { float f; unsigned u; } c; c.f = f;
  unsigned u = c.u;
  return (u16)((u + 0x7FFFu + ((u >> 16) & 1u)) >> 16);
}

// gelu(x) = x * (1 - 1/(exp2(K1*x + K2*x^3) + 1)),  K1 = sqrt(2/pi)*2*log2e
__device__ __forceinline__ float gelu_fast(float x) {
  float x2 = x * x;
  float zp = x * __builtin_fmaf(0.10294325f, x2, 2.3022084f);
  float u = __builtin_amdgcn_exp2f(zp);
  float r = __builtin_amdgcn_rcpf(u + 1.0f);   // u=inf -> r=0 -> y=x
  return x * (1.0f - r);
}

__device__ __forceinline__ void gl_lds16(const void* g, void* l) {
  __builtin_amdgcn_global_load_lds(
      (const __attribute__((address_space(1))) unsigned int*)g,
      (__attribute__((address_space(3))) unsigned int*)l, 16, 0, 0);
}

__device__ __forceinline__ int swzr(int row) { return ((row >> 1) & 3) << 4; }

// Transpose one [R][C] f32 plane per expert -> [C][R] bf16. (verified r1/r2)
__global__ void transpose_bf16(const float* __restrict__ in, u16* __restrict__ out,
                               int R, int C) {
  __shared__ float tile[32][33];
  int e = blockIdx.z;
  const float* ip = in + (size_t)e * R * C;
  u16* op = out + (size_t)e * R * C;
  int c0 = blockIdx.x * 32, r0 = blockIdx.y * 32;
  int tx = threadIdx.x & 31, ty = threadIdx.x >> 5;
  for (int i = 0; i < 32; i += 8)
    tile[ty + i][tx] = ip[(size_t)(r0 + ty + i) * C + (c0 + tx)];
  __syncthreads();
  for (int i = 0; i < 32; i += 8)
    op[(size_t)(c0 + ty + i) * R + (r0 + tx)] = f2bf(tile[tx][ty + i]);
}

__global__ void x_to_bf16(const float* __restrict__ x, u16* __restrict__ xbf) {
  int i = blockIdx.x * 256 + threadIdx.x;
  float4 v = ((const float4*)x)[i];
  union { u16 s[4]; u64 ll; } o;
  o.s[0] = f2bf(v.x); o.s[1] = f2bf(v.y); o.s[2] = f2bf(v.z); o.s[3] = f2bf(v.w);
  ((u64*)xbf)[i] = o.ll;
}

__global__ void zero_unmasked(const int* __restrict__ mask, float4* __restrict__ out4) {
  int row = blockIdx.x * 2 + (threadIdx.x >> 7);
  if (mask[row]) return;  // masked rows fully written by gemm2
  out4[(size_t)row * 128 + (threadIdx.x & 127)] = float4{0.f, 0.f, 0.f, 0.f};
}

__global__ void compact_mask(const int* __restrict__ mask, int* __restrict__ idx,
                             int* __restrict__ counts) {
  int e = blockIdx.x;
  __shared__ int wsum[4];
  __shared__ int base;
  if (threadIdx.x == 0) base = 0;
  const int* m = mask + (size_t)e * TOK;
  int lane = threadIdx.x & 63, w = threadIdx.x >> 6;
  for (int c0 = 0; c0 < TOK; c0 += 256) {
    __syncthreads();
    int i = c0 + threadIdx.x;
    int mi = (m[i] != 0);
    unsigned long long b = __ballot(mi);
    if (lane == 0) wsum[w] = __popcll(b);
    __syncthreads();
    int off = base;
    for (int ww = 0; ww < w; ww++) off += wsum[ww];
    off += __popcll(b & ((1ull << lane) - 1ull));
    if (mi) idx[(size_t)e * TOK + off] = i;
    __syncthreads();
    if (threadIdx.x == 0) base += wsum[0] + wsum[1] + wsum[2] + wsum[3];
  }
  __syncthreads();
  if (threadIdx.x == 0) counts[e] = base;
}

// GEMM1: h[cnt x 2048] = gelu(Xc[cnt x 512] @ W1 + b1), per expert. m97 structure:
// 128x128 tile, BK=32, 16 steps, LDS 32 KB dbuf, 4 waves (64x64 each), 4 blocks/CU.
__launch_bounds__(256, 4)
__global__ void gemm1(const u16* __restrict__ xbf, const u16* __restrict__ W1t,
                      const float* __restrict__ b1f, const int* __restrict__ idx,
                      const int* __restrict__ counts, u16* __restrict__ h, int ebase) {
  const int BPE = MT * (NF / 128);
  int bid = blockIdx.x;
  int el = bid / BPE, r = bid % BPE;
  int n0 = (r / MT) * 128, m0 = (r % MT) * 128;
  int e = ebase + el;
  int cnt = counts[e];
  if (m0 >= cnt) return;

  __shared__ __align__(16) u16 As[2][4096];  // [buf][128 t][32 d] bf16, 8 KB/buf
  __shared__ __align__(16) u16 Bs[2][4096];  // [buf][128 f][32 d]

  int tid = threadIdx.x, lane = tid & 63, w = tid >> 6;
  int wm = w & 1, wn = w >> 1;
  int l15 = lane & 15, l4 = lane >> 4;
  const int* idxe = idx + (size_t)e * TOK;

  // staging thread map: shot s covers tile rows s*64 + w*16 + (lane>>2)
  int srow = lane >> 2, scolb = (lane & 3) << 4;
  int ar0 = w * 16 + srow, ar1 = 64 + w * 16 + srow;
  int cm1 = cnt - 1;
  int t0 = idxe[m0 + ar0 <= cm1 ? m0 + ar0 : cm1];
  int t1 = idxe[m0 + ar1 <= cm1 ? m0 + ar1 : cm1];
  const char* xb = (const char*)xbf;
  const char* w1 = (const char*)W1t;
  size_t asrc0 = (size_t)t0 * 1024 + (scolb ^ swzr(ar0));
  size_t asrc1 = (size_t)t1 * 1024 + (scolb ^ swzr(ar1));
  size_t bsrc0 = ((size_t)e * NF + n0 + ar0) * 1024 + (scolb ^ swzr(ar0));
  size_t bsrc1 = ((size_t)e * NF + n0 + ar1) * 1024 + (scolb ^ swzr(ar1));

  int aoff[4], boff[4];
  #pragma unroll
  for (int i = 0; i < 4; i++) {
    int rowa = wm * 64 + i * 16 + l15;
    aoff[i] = rowa * 64 + ((l4 * 16) ^ swzr(rowa));
    int rowb = wn * 64 + i * 16 + l15;
    boff[i] = rowb * 64 + ((l4 * 16) ^ swzr(rowb));
  }

  auto STAGE = [&](int kb, int c) {
    char* ad = (char*)As + c * 8192 + w * 1024 + lane * 16;
    char* bd = (char*)Bs + c * 8192 + w * 1024 + lane * 16;
    gl_lds16(xb + asrc0 + kb * 64, ad);
    gl_lds16(xb + asrc1 + kb * 64, ad + 4096);
    gl_lds16(w1 + bsrc0 + kb * 64, bd);
    gl_lds16(w1 + bsrc1 + kb * 64, bd + 4096);
  };

  f32x4 acc[4][4];
  #pragma unroll
  for (int i = 0; i < 4; i++)
    #pragma unroll
    for (int j = 0; j < 4; j++) acc[i][j] = (f32x4)(0.0f);

  STAGE(0, 0);
  __syncthreads();
  #pragma unroll
  for (int kb = 0; kb < 16; ++kb) {
    int cur = kb & 1;
    if (kb < 15) STAGE(kb + 1, cur ^ 1);
    const char* ab = (const char*)As + cur * 8192;
    const char* bb = (const char*)Bs + cur * 8192;
    bf16x8 a[4], b[4];
    #pragma unroll
    for (int i = 0; i < 4; i++) a[i] = *(const bf16x8*)(ab + aoff[i]);
    #pragma unroll
    for (int j = 0; j < 4; j++) b[j] = *(const bf16x8*)(bb + boff[j]);
    #pragma unroll
    for (int i = 0; i < 4; i++)
      #pragma unroll
      for (int j = 0; j < 4; j++)
        acc[i][j] = __builtin_amdgcn_mfma_f32_16x16x32_bf16(a[i], b[j], acc[i][j], 0, 0, 0);
    __syncthreads();
  }

  // epilogue: gelu + b1 -> h (bf16, compact rows)
  float b1v[4];
  #pragma unroll
  for (int j = 0; j < 4; j++) b1v[j] = b1f[(size_t)e * NF + n0 + wn * 64 + j * 16 + l15];
  #pragma unroll
  for (int i = 0; i < 4; i++) {
    int trow = m0 + wm * 64 + i * 16 + l4 * 4;
    #pragma unroll
    for (int jj = 0; jj < 4; jj++) {
      u16* hrow = h + ((size_t)el * HP + trow + jj) * NF + n0;
      #pragma unroll
      for (int j = 0; j < 4; j++)
        hrow[wn * 64 + j * 16 + l15] = f2bf(gelu_fast(acc[i][j][jj] + b1v[j]));
    }
  }
}

// GEMM2: Y[cnt x 512] = h[cnt x 2048] @ W2 + b2, scatter rows via idx. K=2048, 64 steps.
__launch_bounds__(256, 4)
__global__ void gemm2(const u16* __restrict__ h, const u16* __restrict__ W2t,
                      const float* __restrict__ b2f, const int* __restrict__ idx,
                      const int* __restrict__ counts, float* __restrict__ out, int ebase) {
  const int BPE = MT * (ND / 128);
  int bid = blockIdx.x;
  int el = bid / BPE, r = bid % BPE;
  int n0 = (r / MT) * 128, m0 = (r % MT) * 128;
  int e = ebase + el;
  int cnt = counts[e];
  if (m0 >= cnt) return;

  __shared__ __align__(16) u16 As[2][4096];  // [buf][128 t][32 f]
  __shared__ __align__(16) u16 Bs[2][4096];  // [buf][128 d][32 f]

  int tid = threadIdx.x, lane = tid & 63, w = tid >> 6;
  int wm = w & 1, wn = w >> 1;
  int l15 = lane & 15, l4 = lane >> 4;
  const int* idxe = idx + (size_t)e * TOK;

  int srow = lane >> 2, scolb = (lane & 3) << 4;
  int ar0 = w * 16 + srow, ar1 = 64 + w * 16 + srow;
  const char* hb = (const char*)h;
  const char* w2 = (const char*)W2t;
  size_t asrc0 = ((size_t)el * HP + m0 + ar0) * 4096 + (scolb ^ swzr(ar0));
  size_t asrc1 = ((size_t)el * HP + m0 + ar1) * 4096 + (scolb ^ swzr(ar1));
  size_t bsrc0 = ((size_t)e * ND + n0 + ar0) * 4096 + (scolb ^ swzr(ar0));
  size_t bsrc1 = ((size_t)e * ND + n0 + ar1) * 4096 + (scolb ^ swzr(ar1));

  int aoff[4], boff[4];
  #pragma unroll
  for (int i = 0; i < 4; i++) {
    int rowa = wm * 64 + i * 16 + l15;
    aoff[i] = rowa * 64 + ((l4 * 16) ^ swzr(rowa));
    int rowb = wn * 64 + i * 16 + l15;
    boff[i] = rowb * 64 + ((l4 * 16) ^ swzr(rowb));
  }

  auto STAGE = [&](int kb, int c) {
    char* ad = (char*)As + c * 8192 + w * 1024 + lane * 16;
    char* bd = (char*)Bs + c * 8192 + w * 1024 + lane * 16;
    gl_lds16(hb + asrc0 + kb * 64, ad);
    gl_lds16(hb + asrc1 + kb * 64, ad + 4096);
    gl_lds16(w2 + bsrc0 + kb * 64, bd);
    gl_lds16(w2 + bsrc1 + kb * 64, bd + 4096);
  };

  f32x4 acc[4][4];
  #pragma unroll
  for (int i = 0; i < 4; i++)
    #pragma unroll
    for (int j = 0; j < 4; j++) acc[i][j] = (f32x4)(0.0f);

  STAGE(0, 0);
  __syncthreads();
  #pragma unroll 2
  for (int kb = 0; kb < 64; ++kb) {
    int cur = kb & 1;
    if (kb < 63) STAGE(kb + 1, cur ^ 1);
    const char* ab = (const char*)As + cur * 8192;
    const char* bb = (const char*)Bs + cur * 8192;
    bf16x8 a[4], b[4];
    #pragma unroll
    for (int i = 0; i < 4; i++) a[i] = *(const bf16x8*)(ab + aoff[i]);
    #pragma unroll
    for (int j = 0; j < 4; j++) b[j] = *(const bf16x8*)(bb + boff[j]);
    #pragma unroll
    for (int i = 0; i < 4; i++)
      #pragma unroll
      for (int j = 0; j < 4; j++)
        acc[i][j] = __builtin_amdgcn_mfma_f32_16x16x32_bf16(a[i], b[j], acc[i][j], 0, 0, 0);
    __syncthreads();
  }

  // epilogue: + b2, scatter masked rows (f32, 64-B segments)
  float b2v[4];
  #pragma unroll
  for (int j = 0; j < 4; j++) b2v[j] = b2f[(size_t)e * ND + n0 + wn * 64 + j * 16 + l15];
  #pragma unroll
  for (int i = 0; i < 4; i++) {
    #pragma unroll
    for (int jj = 0; jj < 4; jj++) {
      int row = m0 + wm * 64 + i * 16 + l4 * 4 + jj;
      if (row < cnt) {
        int tok = idxe[row];
        float* orow = out + ((size_t)e * TOK + tok) * ND + n0;
        #pragma unroll
        for (int j = 0; j < 4; j++)
          orow[wn * 64 + j * 16 + l15] = acc[i][j][jj] + b2v[j];
      }
    }
  }
}

extern "C" void kernel_launch(void* const* d_in, const int* in_sizes, int n_in,
                              void* d_out, int out_size, void* d_ws, size_t ws_size,
                              hipStream_t stream) {
  const float* x  = (const float*)d_in[0];
  const float* W1 = (const float*)d_in[1];
  const float* b1 = (const float*)d_in[2];
  const float* W2 = (const float*)d_in[3];
  const float* b2 = (const float*)d_in[4];
  const int* mask = (const int*)d_in[5];

  char* ws = (char*)d_ws;
  int* counts = (int*)ws;                                   // 1 KiB
  int* idx    = (int*)(ws + 1024);                          // 512 KiB
  u16* W1t    = (u16*)(ws + 1024 + (size_t)NE * TOK * 4);   // 16 MiB  [E][f][d]
  u16* W2t    = W1t + (size_t)NE * NF * ND;                 // 16 MiB  [E][d][f]
  u16* xbf    = W2t + (size_t)NE * ND * NF;                 // 16 MiB
  u16* h      = xbf + (size_t)TOK * ND;                     // 75.5 MiB [4][HP][NF]

  zero_unmasked<<<dim3(NE * TOK / 2), dim3(256), 0, stream>>>(mask, (float4*)d_out);
  transpose_bf16<<<dim3(NF / 32, ND / 32, NE), dim3(256), 0, stream>>>(W1, W1t, ND, NF);
  transpose_bf16<<<dim3(ND / 32, NF / 32, NE), dim3(256), 0, stream>>>(W2, W2t, NF, ND);
  x_to_bf16<<<dim3(TOK * ND / 4 / 256), dim3(256), 0, stream>>>(x, xbf);
  compact_mask<<<dim3(NE), dim3(256), 0, stream>>>(mask, idx, counts);

  for (int p = 0; p < 2; p++) {
    gemm1<<<dim3(4 * MT * (NF / 128)), dim3(256), 0, stream>>>(
        xbf, W1t, b1, idx, counts, h, p * 4);
    gemm2<<<dim3(4 * MT * (ND / 128)), dim3(256), 0, stream>>>(
        h, W2t, b2, idx, counts, (float*)d_out, p * 4);
  }
}